// Round 7
// baseline (404.424 us; speedup 1.0000x reference)
//
#include <hip/hip_runtime.h>

#define N_TOKENS   65536
#define NUM_CODES  4096
#define EMBED_DIM  256

#define IDX_OFF  ((size_t)N_TOKENS * EMBED_DIM)
#define LOSS_OFF (IDX_OFF + N_TOKENS)

#define DELTA 0.2f
#define UCAP  16384
#define RT    8        // tokens per refine block

typedef _Float16 half8 __attribute__((ext_vector_type(8)));
typedef float    f32x4 __attribute__((ext_vector_type(4)));
typedef unsigned long long u64;

__device__ __forceinline__ void gl_lds16(const void* g, void* l) {
    __builtin_amdgcn_global_load_lds(
        (const __attribute__((address_space(1))) unsigned int*)g,
        (__attribute__((address_space(3))) unsigned int*)l, 16, 0, 0);
}

// ---------------- converter: E (f32) -> B-fragment-packed fp16 ----------------
// Eh layout: [ct=code>>4][kc=0..7][lane=q*16+(code&15)] x 16B
//   frag(ct,kc): lane l holds E[ct*16 + (l&15)][kc*32 + (l>>4)*8 + j], j=0..7
__global__ void k_convE(const float* __restrict__ E, _Float16* __restrict__ Eh) {
    int gid = blockIdx.x * 256 + threadIdx.x;   // NUM_CODES*32 threads
    int n  = gid >> 5;
    int kg = gid & 31;
    const float* src = E + (size_t)n * EMBED_DIM + kg * 8;
    float4 a = *(const float4*)src;
    float4 b = *(const float4*)(src + 4);
    int ct = n >> 4, l15 = n & 15, kc = kg >> 2, q = kg & 3;
    int lane = q * 16 + l15;
    half8 hv;
    hv[0]=(_Float16)a.x; hv[1]=(_Float16)a.y; hv[2]=(_Float16)a.z; hv[3]=(_Float16)a.w;
    hv[4]=(_Float16)b.x; hv[5]=(_Float16)b.y; hv[6]=(_Float16)b.z; hv[7]=(_Float16)b.w;
    *(half8*)(Eh + ((size_t)(ct * 8 + kc) * 64 + lane) * 8) = hv;
}

// ---------------- per-code squared norms (exact fp32) ----------------
__global__ void k_esq(const float* __restrict__ E, float* __restrict__ esq) {
    int k = blockIdx.x;
    int l = threadIdx.x;
    float4 v = *(const float4*)(E + (size_t)k * EMBED_DIM + l * 4);
    float s = v.x * v.x + v.y * v.y + v.z * v.z + v.w * v.w;
    #pragma unroll
    for (int off = 32; off; off >>= 1) s += __shfl_down(s, off, 64);
    if (l == 0) esq[k] = s;
}

// ---------------- transpose E -> Et[256][4096] (for refine) ----------------
__global__ void k_transpose(const float* __restrict__ E, float* __restrict__ Et) {
    __shared__ float t[32][33];
    int tx = threadIdx.x & 31, ty = threadIdx.x >> 5;
    int c0 = blockIdx.x * 32, d0 = blockIdx.y * 32;
    #pragma unroll
    for (int i = 0; i < 4; ++i)
        t[ty + 8 * i][tx] = E[(size_t)(c0 + ty + 8 * i) * EMBED_DIM + d0 + tx];
    __syncthreads();
    #pragma unroll
    for (int i = 0; i < 4; ++i)
        Et[(size_t)(d0 + ty + 8 * i) * NUM_CODES + c0 + tx] = t[tx][ty + 8 * i];
}

// ---------------- fused fp16-MFMA distance + argmin/second (v9, resubmit) ----
// v9 occupancy fix: grid was the binding constraint all along (512 blocks = 2/CU;
// LDS/VGPR allowed more but no blocks existed to fill them).
// block: 256 thr = 4 waves, 64 tokens; wave = 32 tok x 32 codes (half tile).
// grid = 1024 = exactly 4 blocks/CU resident (32 KB LDS each, VGPR ~110).
// Four independent 4-wave blocks per CU overlap each other's stage-drain and
// barrier stalls (m114 mechanism). esq_s dropped from LDS to fit: the 2 per-lane
// esq values are read from global (16 KB table, L1-resident), issued before the
// MFMA cluster so their latency hides under it.
// (Round-6 run died in the container infra before producing a result; kernel
// audit found no hang/fault path -- resubmitted unchanged for a clean measure.)
__global__ __launch_bounds__(256)
void k_argmin_mfma(const float* __restrict__ Z, const _Float16* __restrict__ Eh,
                   const float* __restrict__ esq, int* __restrict__ out_idx,
                   int* __restrict__ ulist, int* __restrict__ ucount) {
    __shared__ __align__(16) _Float16 Bs[16384];   // 32 KB: 64 codes x 256 K

    const int tid  = threadIdx.x;
    const int lane = tid & 63;
    const int w    = tid >> 6;
    const int w0   = w >> 1;     // token group (0..1): 32 tokens each
    const int w1   = w & 1;      // code half
    const int l15  = lane & 15;
    const int q    = lane >> 4;
    const int tb   = blockIdx.x;
    const int cb   = w1 * 2;     // this wave's 2 ct of the tile's 4

    // stage: wave w fills frag-rows w*8..w*8+7 of the 64-code tile (8 KB/wave).
#define STAGE(itn) do {                                                            \
        const _Float16* _src = Eh + ((size_t)(itn) << 14) + (w * 8) * 512 + lane * 8; \
        _Pragma("unroll")                                                          \
        for (int s = 0; s < 8; ++s)                                                \
            gl_lds16(_src + s * 512, Bs + (w * 8 + s) * 512);                      \
    } while (0)

    // A-fragments: frag(rt,kc): lane holds Z[tb*64 + w0*32 + rt*16 + l15][kc*32 + q*8 + j]
    half8 A[2][8];
    const float* Zb = Z + ((size_t)tb * 64 + w0 * 32) * EMBED_DIM;
    #pragma unroll
    for (int rt = 0; rt < 2; ++rt) {
        const float* Zr = Zb + (rt * 16 + l15) * EMBED_DIM + q * 8;
        #pragma unroll
        for (int kc = 0; kc < 8; ++kc) {
            float4 a = *(const float4*)(Zr + kc * 32);
            float4 b = *(const float4*)(Zr + kc * 32 + 4);
            half8 hv;
            hv[0]=(_Float16)a.x; hv[1]=(_Float16)a.y; hv[2]=(_Float16)a.z; hv[3]=(_Float16)a.w;
            hv[4]=(_Float16)b.x; hv[5]=(_Float16)b.y; hv[6]=(_Float16)b.z; hv[7]=(_Float16)b.w;
            A[rt][kc] = hv;
        }
    }

    float best[8], sec[8];
    int   bidx[8];
    #pragma unroll
    for (int k = 0; k < 8; ++k) { best[k] = 1e30f; sec[k] = 1e30f; bidx[k] = 0; }

    for (int it = 0; it < NUM_CODES / 64; ++it) {
        __syncthreads();                 // previous tile fully consumed
        STAGE(it);
        __syncthreads();                 // stage complete (vmcnt+lgkm drained)

        const int code0 = it * 64 + cb * 16 + l15;
        const int code1 = code0 + 16;
        float e0 = esq[code0];           // L1-resident; latency hides under MFMA
        float e1 = esq[code1];

        f32x4 acc[2][2];
        #pragma unroll
        for (int rt = 0; rt < 2; ++rt) { acc[rt][0] = (f32x4)0.0f; acc[rt][1] = (f32x4)0.0f; }

        __builtin_amdgcn_s_setprio(1);
        #pragma unroll
        for (int kc = 0; kc < 8; ++kc) {
            half8 bf0 = *(const half8*)(Bs + ((cb + 0) * 8 + kc) * 512 + lane * 8);
            half8 bf1 = *(const half8*)(Bs + ((cb + 1) * 8 + kc) * 512 + lane * 8);
            #pragma unroll
            for (int rt = 0; rt < 2; ++rt) {
                acc[rt][0] = __builtin_amdgcn_mfma_f32_16x16x32_f16(A[rt][kc], bf0, acc[rt][0], 0, 0, 0);
                acc[rt][1] = __builtin_amdgcn_mfma_f32_16x16x32_f16(A[rt][kc], bf1, acc[rt][1], 0, 0, 0);
            }
        }
        __builtin_amdgcn_s_setprio(0);

        // epilogue: d2 = esq - 2*dot; code-pair tournament (strict-<, lower index
        // wins ties), exact 2nd-min maintenance.
        #pragma unroll
        for (int rt = 0; rt < 2; ++rt)
            #pragma unroll
            for (int r = 0; r < 4; ++r) {
                int k = rt * 4 + r;
                float v0 = fmaf(-2.0f, acc[rt][0][r], e0);
                float v1 = fmaf(-2.0f, acc[rt][1][r], e1);
                bool pw  = v1 < v0;
                float wv = pw ? v1 : v0;       // pair winner
                float lv = pw ? v0 : v1;       // pair loser
                int   wi = pw ? code1 : code0;
                float ob = best[k];
                bool t = wv < ob;
                sec[k]  = fminf(fminf(fmaxf(ob, wv), lv), sec[k]);
                best[k] = t ? wv : ob;
                bidx[k] = t ? wi : bidx[k];
            }
    }
#undef STAGE

    // in-wave reduce over the 16 col-lanes (l15) of each quad group
    #pragma unroll
    for (int m = 1; m <= 8; m <<= 1) {
        #pragma unroll
        for (int k = 0; k < 8; ++k) {
            float ob = __shfl_xor(best[k], m, 64);
            float os = __shfl_xor(sec[k],  m, 64);
            int   oi = __shfl_xor(bidx[k], m, 64);
            float ns = fminf(fminf(sec[k], os), fmaxf(best[k], ob));
            bool t = (ob < best[k]) || (ob == best[k] && oi < bidx[k]);
            best[k] = t ? ob : best[k];
            bidx[k] = t ? oi : bidx[k];
            sec[k]  = ns;
        }
    }

    // cross-code-half merge via LDS (reuse Bs): 64 token rows x 2 halves
    __syncthreads();
    float* mb = (float*)Bs;          // [64][2]
    float* ms = mb + 128;
    int*   mi = (int*)(mb + 256);
    if (l15 == 0) {
        #pragma unroll
        for (int k = 0; k < 8; ++k) {
            int row = w0 * 32 + (k >> 2) * 16 + q * 4 + (k & 3);
            mb[row * 2 + w1] = best[k];
            ms[row * 2 + w1] = sec[k];
            mi[row * 2 + w1] = bidx[k];
        }
    }
    __syncthreads();
    if (tid < 64) {
        float b0 = mb[tid * 2], b1 = mb[tid * 2 + 1];
        float s0 = ms[tid * 2], s1 = ms[tid * 2 + 1];
        int   i0 = mi[tid * 2], i1 = mi[tid * 2 + 1];
        bool t = (b1 < b0) || (b1 == b0 && i1 < i0);
        float bb = t ? b1 : b0;
        int   ii = t ? i1 : i0;
        float ss = fminf(fminf(s0, s1), fmaxf(b0, b1));
        int token = tb * 64 + tid;
        out_idx[token] = ii;
        if (ss - bb < DELTA) {
            int p = atomicAdd(ucount, 1);
            if (p < UCAP) ulist[p] = token;
        }
    }
}

// ---------------- exact fp32 re-scan of uncertain tokens ----------------
__launch_bounds__(256)
__global__ void k_refine(const float* __restrict__ Z, const float* __restrict__ Et,
                         const float* __restrict__ esq, const int* __restrict__ ulist,
                         const int* __restrict__ ucount, u64* __restrict__ umin) {
    int cnt = *ucount; if (cnt > UCAP) cnt = UCAP;
    const int g   = blockIdx.x >> 2;
    const int qtr = blockIdx.x & 3;
    if (g * RT >= cnt) return;

    __shared__ float zs[RT][256];
    const int tid  = threadIdx.x;
    const int lane = tid & 63;

    #pragma unroll
    for (int t = 0; t < RT; ++t) {
        int u = g * RT + t;
        int tok = ulist[(u < cnt) ? u : g * RT];
        zs[t][tid] = Z[(size_t)tok * EMBED_DIM + tid];
    }
    __syncthreads();

    const int c0 = qtr * 1024 + tid * 4;
    f32x4 acc[RT];
    #pragma unroll
    for (int t = 0; t < RT; ++t) acc[t] = (f32x4)0.0f;

    for (int d4 = 0; d4 < 64; ++d4) {
        f32x4 e0 = *(const f32x4*)(Et + (size_t)(d4 * 4 + 0) * NUM_CODES + c0);
        f32x4 e1 = *(const f32x4*)(Et + (size_t)(d4 * 4 + 1) * NUM_CODES + c0);
        f32x4 e2 = *(const f32x4*)(Et + (size_t)(d4 * 4 + 2) * NUM_CODES + c0);
        f32x4 e3 = *(const f32x4*)(Et + (size_t)(d4 * 4 + 3) * NUM_CODES + c0);
        #pragma unroll
        for (int t = 0; t < RT; ++t) {
            f32x4 z4 = *(const f32x4*)&zs[t][d4 * 4];
            acc[t] += z4.x * e0;
            acc[t] += z4.y * e1;
            acc[t] += z4.z * e2;
            acc[t] += z4.w * e3;
        }
    }

    f32x4 eq = *(const f32x4*)(esq + c0);
    #pragma unroll
    for (int t = 0; t < RT; ++t) {
        u64 p = ~0ull;
        #pragma unroll
        for (int r = 0; r < 4; ++r) {
            float v = fmaf(-2.0f, acc[t][r], eq[r]) + 4096.0f;
            u64 cand = ((u64)__float_as_uint(v) << 32) | (unsigned)(c0 + r);
            p = cand < p ? cand : p;
        }
        #pragma unroll
        for (int m = 1; m <= 32; m <<= 1) {
            u64 o = __shfl_xor(p, m, 64);
            p = o < p ? o : p;
        }
        int u = g * RT + t;
        if (lane == 0 && u < cnt) atomicMin(umin + u, p);
    }
}

__global__ void k_rwrite(const int* __restrict__ ulist, const int* __restrict__ ucount,
                         const u64* __restrict__ umin, int* __restrict__ out_idx) {
    int cnt = *ucount; if (cnt > UCAP) cnt = UCAP;
    int u = blockIdx.x * 256 + threadIdx.x;
    if (u < cnt) out_idx[ulist[u]] = (int)(umin[u] & 0xFFFFFFFFu);
}

// ---------------- gather z_q, loss partials, histogram ----------------
__global__ void k_gather(const float* __restrict__ Z, const float* __restrict__ E,
                         float* __restrict__ out,
                         float* __restrict__ loss_parts, unsigned* __restrict__ hist) {
    int wave = threadIdx.x >> 6, lane = threadIdx.x & 63;
    int token = blockIdx.x * 4 + wave;
    int* idxi = (int*)(out + IDX_OFF);
    int k = idxi[token];
    float4 z = *(const float4*)(Z + (size_t)token * EMBED_DIM + lane * 4);
    float4 qv = *(const float4*)(E + (size_t)k * EMBED_DIM + lane * 4);
    *(float4*)(out + (size_t)token * EMBED_DIM + lane * 4) = qv;
    float dx = qv.x - z.x, dy = qv.y - z.y, dz = qv.z - z.z, dw = qv.w - z.w;
    float s = dx * dx + dy * dy + dz * dz + dw * dw;
    #pragma unroll
    for (int off = 32; off; off >>= 1) s += __shfl_down(s, off, 64);
    if (lane == 0) {
        atomicAdd(loss_parts + (blockIdx.x & 1023), s);
        atomicAdd(hist + k, 1u);
        out[IDX_OFF + token] = (float)k;
    }
}

// ---------------- finalize loss + perplexity ----------------
__global__ void k_final(const float* __restrict__ loss_parts,
                        const unsigned* __restrict__ hist, float* __restrict__ out) {
    __shared__ float red[256];
    int t = threadIdx.x;
    float s = 0.0f;
    for (int i = t; i < 1024; i += 256) s += loss_parts[i];
    red[t] = s;
    __syncthreads();
    #pragma unroll
    for (int off = 128; off; off >>= 1) {
        if (t < off) red[t] += red[t + off];
        __syncthreads();
    }
    float loss = 0.1f * red[0] / (float)(N_TOKENS * EMBED_DIM);

    float h = 0.0f;
    for (int i = t; i < NUM_CODES; i += 256) {
        float p = (float)hist[i] / (float)N_TOKENS;
        h += p * logf(p + 1e-10f);
    }
    __syncthreads();
    red[t] = h;
    __syncthreads();
    #pragma unroll
    for (int off = 128; off; off >>= 1) {
        if (t < off) red[t] += red[t + off];
        __syncthreads();
    }
    if (t == 0) {
        out[LOSS_OFF]     = loss;
        out[LOSS_OFF + 1] = expf(-red[0]);
    }
}

extern "C" void kernel_launch(void* const* d_in, const int* in_sizes, int n_in,
                              void* d_out, int out_size, void* d_ws, size_t ws_size,
                              hipStream_t stream) {
    const float* Z = (const float*)d_in[0];
    const float* E = (const float*)d_in[1];
    float* out = (float*)d_out;
    char*  ob  = (char*)d_out;
    char*  ws  = (char*)d_ws;

    // scratch in d_out's upper z_q region (overwritten by gather afterwards):
    _Float16* Eh   = (_Float16*)(ob + 50331648);          // 48 MB: 2 MB packed
    float*    Et   = (float*)(ob + 54525952);             // 52 MB: 4 MB
    u64*      umin = (u64*)(ob + 58720256);               // 56 MB: 128 KB
    int*      idx  = (int*)(out + IDX_OFF);

    // small ws scratch (~100 KB)
    float*    esq        = (float*)ws;                    // 16 KB
    int*      ulist      = (int*)(ws + 16384);            // 64 KB
    int*      ucount     = (int*)(ws + 81920);            // 64 B
    float*    loss_parts = (float*)(ws + 81984);          // 4 KB
    unsigned* hist       = (unsigned*)(ws + 86080);       // 16 KB

    hipMemsetAsync(ws + 81920, 0, 64 + 4096 + 16384, stream);
    hipMemsetAsync(umin, 0xFF, (size_t)UCAP * 8, stream);

    k_convE      <<<(NUM_CODES * 32) / 256, 256, 0, stream>>>(E, Eh);
    k_esq        <<<NUM_CODES, 64, 0, stream>>>(E, esq);
    k_transpose  <<<dim3(NUM_CODES / 32, EMBED_DIM / 32), 256, 0, stream>>>(E, Et);
    k_argmin_mfma<<<N_TOKENS / 64, 256, 0, stream>>>(Z, Eh, esq, idx, ulist, ucount);
    k_refine     <<<4 * (UCAP / RT), 256, 0, stream>>>(Z, Et, esq, ulist, ucount, umin);
    k_rwrite     <<<UCAP / 256, 256, 0, stream>>>(ulist, ucount, umin, idx);
    k_gather     <<<N_TOKENS / 4, 256, 0, stream>>>(Z, E, out, loss_parts, hist);
    k_final      <<<1, 256, 0, stream>>>(loss_parts, hist, out);
}

// Round 8
// 375.229 us; speedup vs baseline: 1.0778x; 1.0778x over previous
//
#include <hip/hip_runtime.h>

#define N_TOKENS   65536
#define NUM_CODES  4096
#define EMBED_DIM  256

#define IDX_OFF  ((size_t)N_TOKENS * EMBED_DIM)
#define LOSS_OFF (IDX_OFF + N_TOKENS)

#define DELTA 0.2f
#define UCAP  16384
#define RT    8        // tokens per refine block

typedef _Float16 half8 __attribute__((ext_vector_type(8)));
typedef float    f32x4 __attribute__((ext_vector_type(4)));
typedef unsigned long long u64;

__device__ __forceinline__ void gl_lds16(const void* g, void* l) {
    __builtin_amdgcn_global_load_lds(
        (const __attribute__((address_space(1))) unsigned int*)g,
        (__attribute__((address_space(3))) unsigned int*)l, 16, 0, 0);
}

// ---------------- converter: E (f32) -> B-fragment-packed fp16 ----------------
// Eh layout: [ct=code>>4][kc=0..7][lane=q*16+(code&15)] x 16B
//   frag(ct,kc): lane l holds E[ct*16 + (l&15)][kc*32 + (l>>4)*8 + j], j=0..7
__global__ void k_convE(const float* __restrict__ E, _Float16* __restrict__ Eh) {
    int gid = blockIdx.x * 256 + threadIdx.x;   // NUM_CODES*32 threads
    int n  = gid >> 5;
    int kg = gid & 31;
    const float* src = E + (size_t)n * EMBED_DIM + kg * 8;
    float4 a = *(const float4*)src;
    float4 b = *(const float4*)(src + 4);
    int ct = n >> 4, l15 = n & 15, kc = kg >> 2, q = kg & 3;
    int lane = q * 16 + l15;
    half8 hv;
    hv[0]=(_Float16)a.x; hv[1]=(_Float16)a.y; hv[2]=(_Float16)a.z; hv[3]=(_Float16)a.w;
    hv[4]=(_Float16)b.x; hv[5]=(_Float16)b.y; hv[6]=(_Float16)b.z; hv[7]=(_Float16)b.w;
    *(half8*)(Eh + ((size_t)(ct * 8 + kc) * 64 + lane) * 8) = hv;
}

// ---------------- per-code squared norms (exact fp32) ----------------
__global__ void k_esq(const float* __restrict__ E, float* __restrict__ esq) {
    int k = blockIdx.x;
    int l = threadIdx.x;
    float4 v = *(const float4*)(E + (size_t)k * EMBED_DIM + l * 4);
    float s = v.x * v.x + v.y * v.y + v.z * v.z + v.w * v.w;
    #pragma unroll
    for (int off = 32; off; off >>= 1) s += __shfl_down(s, off, 64);
    if (l == 0) esq[k] = s;
}

// ---------------- transpose E -> Et[256][4096] (for refine) ----------------
__global__ void k_transpose(const float* __restrict__ E, float* __restrict__ Et) {
    __shared__ float t[32][33];
    int tx = threadIdx.x & 31, ty = threadIdx.x >> 5;
    int c0 = blockIdx.x * 32, d0 = blockIdx.y * 32;
    #pragma unroll
    for (int i = 0; i < 4; ++i)
        t[ty + 8 * i][tx] = E[(size_t)(c0 + ty + 8 * i) * EMBED_DIM + d0 + tx];
    __syncthreads();
    #pragma unroll
    for (int i = 0; i < 4; ++i)
        Et[(size_t)(d0 + ty + 8 * i) * NUM_CODES + c0 + tx] = t[tx][ty + 8 * i];
}

// ---------------- fused fp16-MFMA distance + argmin/second (v10) ----------------
// v10: amortize per-iteration overhead (stage drain + barriers, ~3500 cyc/iter --
// the calibrated non-MFMA cost that held MfmaUtil at 37%) by DOUBLING the tile:
// block = 512 thr = 8 waves, 128 tokens; per iter 128 codes => only 32 iters.
// wave = 32 tok (wt=w>>1) x 64 codes (wc=w&1 half). A[2][8]=64 regs (v6-proven
// no-spill footprint). LDS: 2 x 64 KB double-buffer + 16 KB esq = 144 KB,
// 1 block/CU, 8 waves (same waves/CU as all prior variants -- the win is purely
// halving the count of fixed-overhead iterations).
// Counted-vmcnt schedule identical to v6 (proven correct): s_waitcnt vmcnt(8)
// keeps next tile's 8 gl_lds in flight across the barrier; vmcnt(0) only at the
// last iter. Epilogue = v6's verified 4-way tournament; merge = v9's verified
// cross-half LDS merge.
__global__ __launch_bounds__(512)
void k_argmin_mfma(const float* __restrict__ Z, const _Float16* __restrict__ Eh,
                   const float* __restrict__ esq, int* __restrict__ out_idx,
                   int* __restrict__ ulist, int* __restrict__ ucount) {
    __shared__ __align__(16) _Float16 Bs[2][32768];   // 2 x 64 KB: 128 codes x 256 K
    __shared__ float esq_s[NUM_CODES];                // 16 KB  (total 144 KB)

    const int tid  = threadIdx.x;
    const int lane = tid & 63;
    const int w    = tid >> 6;    // 0..7
    const int wt   = w >> 1;      // token group (0..3): 32 tokens each
    const int wc   = w & 1;       // code half (0..1): 64 codes each
    const int l15  = lane & 15;
    const int q    = lane >> 4;
    const int tb   = blockIdx.x;

    // stage: tile it = 64 frag-rows x 1 KB at Eh + it*32768; wave w stages rows
    // w*8..w*8+7 (8 KB). In-loop VMEM = ONLY these 8 gl_lds/wave/tile -> vmcnt exact.
#define STAGE(itn, bb) do {                                                        \
        const _Float16* _src = Eh + ((size_t)(itn) << 15) + (w * 8) * 512 + lane * 8; \
        _Float16* _dst = &Bs[bb][(w * 8) * 512];                                   \
        _Pragma("unroll")                                                          \
        for (int s = 0; s < 8; ++s)                                                \
            gl_lds16(_src + s * 512, _dst + s * 512);                              \
    } while (0)

    STAGE(0, 0);
    STAGE(1, 1);

    for (int i = tid; i < NUM_CODES; i += 512) esq_s[i] = esq[i];

    // A-fragments: frag(rt,kc): lane holds Z[tb*128 + wt*32 + rt*16 + l15][kc*32 + q*8 + j]
    half8 A[2][8];
    const float* Zb = Z + ((size_t)tb * 128 + wt * 32) * EMBED_DIM;
    #pragma unroll
    for (int rt = 0; rt < 2; ++rt) {
        const float* Zr = Zb + (rt * 16 + l15) * EMBED_DIM + q * 8;
        #pragma unroll
        for (int kc = 0; kc < 8; ++kc) {
            float4 a = *(const float4*)(Zr + kc * 32);
            float4 b = *(const float4*)(Zr + kc * 32 + 4);
            half8 hv;
            hv[0]=(_Float16)a.x; hv[1]=(_Float16)a.y; hv[2]=(_Float16)a.z; hv[3]=(_Float16)a.w;
            hv[4]=(_Float16)b.x; hv[5]=(_Float16)b.y; hv[6]=(_Float16)b.z; hv[7]=(_Float16)b.w;
            A[rt][kc] = hv;
        }
    }

    float best[8], sec[8];
    int   bidx[8];
    #pragma unroll
    for (int k = 0; k < 8; ++k) { best[k] = 1e30f; sec[k] = 1e30f; bidx[k] = 0; }

    __syncthreads();   // full drain ONCE: tiles 0,1 staged, esq_s + A ready

    const int NIT = NUM_CODES / 128;    // 32
    for (int it = 0; it < NIT; ++it) {
        const int b = it & 1;

        // wait for THIS tile's stage only; tile it+1's 8 loads stay in flight.
        if (it == NIT - 1) asm volatile("s_waitcnt vmcnt(0)" ::: "memory");
        else               asm volatile("s_waitcnt vmcnt(8)" ::: "memory");
        asm volatile("s_barrier" ::: "memory");

        f32x4 acc[2][4];
        #pragma unroll
        for (int rt = 0; rt < 2; ++rt)
            #pragma unroll
            for (int c = 0; c < 4; ++c) acc[rt][c] = (f32x4)0.0f;

        __builtin_amdgcn_s_setprio(1);
        #pragma unroll
        for (int kc = 0; kc < 8; ++kc) {
            half8 bf[4];
            #pragma unroll
            for (int c = 0; c < 4; ++c)
                bf[c] = *(const half8*)(&Bs[b][((wc * 4 + c) * 8 + kc) * 512 + lane * 8]);
            #pragma unroll
            for (int rt = 0; rt < 2; ++rt)
                #pragma unroll
                for (int c = 0; c < 4; ++c)
                    acc[rt][c] = __builtin_amdgcn_mfma_f32_16x16x32_f16(A[rt][kc], bf[c], acc[rt][c], 0, 0, 0);
        }
        __builtin_amdgcn_s_setprio(0);

        asm volatile("s_barrier" ::: "memory");   // all waves done reading Bs[b]
        if (it + 2 < NIT) STAGE(it + 2, b);       // issue early (T14)

        // epilogue (hides stage latency): d2 = esq - 2*dot; 4-way tournament,
        // strict-<, lowest-index-on-tie; exact 2nd-min maintenance (v6-verified).
        const int code_base = it * 128 + wc * 64 + l15;
        float e0 = esq_s[code_base];
        float e1 = esq_s[code_base + 16];
        float e2 = esq_s[code_base + 32];
        float e3 = esq_s[code_base + 48];
        #pragma unroll
        for (int rt = 0; rt < 2; ++rt)
            #pragma unroll
            for (int r = 0; r < 4; ++r) {
                int k = rt * 4 + r;
                float v0 = fmaf(-2.0f, acc[rt][0][r], e0);
                float v1 = fmaf(-2.0f, acc[rt][1][r], e1);
                float v2 = fmaf(-2.0f, acc[rt][2][r], e2);
                float v3 = fmaf(-2.0f, acc[rt][3][r], e3);
                bool t01 = v1 < v0;
                float w01 = t01 ? v1 : v0, l01 = t01 ? v0 : v1;
                int   i01 = code_base + (t01 ? 16 : 0);
                bool t23 = v3 < v2;
                float w23 = t23 ? v3 : v2, l23 = t23 ? v2 : v3;
                int   i23 = code_base + 32 + (t23 ? 16 : 0);
                bool tf = w23 < w01;
                float wv = tf ? w23 : w01;
                int   wi = tf ? i23 : i01;
                float rsec = fminf(fminf(fmaxf(w01, w23), l01), l23);
                float ob = best[k];
                bool tb_ = wv < ob;
                sec[k]  = fminf(fminf(sec[k], rsec), fmaxf(ob, wv));
                best[k] = tb_ ? wv : ob;
                bidx[k] = tb_ ? wi : bidx[k];
            }
    }
#undef STAGE

    // in-wave reduce over the 16 col-lanes (l15) of each quad group
    #pragma unroll
    for (int m = 1; m <= 8; m <<= 1) {
        #pragma unroll
        for (int k = 0; k < 8; ++k) {
            float ob = __shfl_xor(best[k], m, 64);
            float os = __shfl_xor(sec[k],  m, 64);
            int   oi = __shfl_xor(bidx[k], m, 64);
            float ns = fminf(fminf(sec[k], os), fmaxf(best[k], ob));
            bool t = (ob < best[k]) || (ob == best[k] && oi < bidx[k]);
            best[k] = t ? ob : best[k];
            bidx[k] = t ? oi : bidx[k];
            sec[k]  = ns;
        }
    }

    // cross-code-half merge via LDS (reuse Bs): 128 token rows x 2 halves
    __syncthreads();
    float* mb = (float*)Bs;          // [128][2]
    float* ms = mb + 256;
    int*   mi = (int*)(mb + 512);
    if (l15 == 0) {
        #pragma unroll
        for (int k = 0; k < 8; ++k) {
            int row = wt * 32 + (k >> 2) * 16 + q * 4 + (k & 3);
            mb[row * 2 + wc] = best[k];
            ms[row * 2 + wc] = sec[k];
            mi[row * 2 + wc] = bidx[k];
        }
    }
    __syncthreads();
    if (tid < 128) {
        float b0 = mb[tid * 2], b1 = mb[tid * 2 + 1];
        float s0 = ms[tid * 2], s1 = ms[tid * 2 + 1];
        int   i0 = mi[tid * 2], i1 = mi[tid * 2 + 1];
        bool t = (b1 < b0) || (b1 == b0 && i1 < i0);
        float bb = t ? b1 : b0;
        int   ii = t ? i1 : i0;
        float ss = fminf(fminf(s0, s1), fmaxf(b0, b1));
        int token = tb * 128 + tid;
        out_idx[token] = ii;
        if (ss - bb < DELTA) {
            int p = atomicAdd(ucount, 1);
            if (p < UCAP) ulist[p] = token;
        }
    }
}

// ---------------- exact fp32 re-scan of uncertain tokens ----------------
__launch_bounds__(256)
__global__ void k_refine(const float* __restrict__ Z, const float* __restrict__ Et,
                         const float* __restrict__ esq, const int* __restrict__ ulist,
                         const int* __restrict__ ucount, u64* __restrict__ umin) {
    int cnt = *ucount; if (cnt > UCAP) cnt = UCAP;
    const int g   = blockIdx.x >> 2;
    const int qtr = blockIdx.x & 3;
    if (g * RT >= cnt) return;

    __shared__ float zs[RT][256];
    const int tid  = threadIdx.x;
    const int lane = tid & 63;

    #pragma unroll
    for (int t = 0; t < RT; ++t) {
        int u = g * RT + t;
        int tok = ulist[(u < cnt) ? u : g * RT];
        zs[t][tid] = Z[(size_t)tok * EMBED_DIM + tid];
    }
    __syncthreads();

    const int c0 = qtr * 1024 + tid * 4;
    f32x4 acc[RT];
    #pragma unroll
    for (int t = 0; t < RT; ++t) acc[t] = (f32x4)0.0f;

    for (int d4 = 0; d4 < 64; ++d4) {
        f32x4 e0 = *(const f32x4*)(Et + (size_t)(d4 * 4 + 0) * NUM_CODES + c0);
        f32x4 e1 = *(const f32x4*)(Et + (size_t)(d4 * 4 + 1) * NUM_CODES + c0);
        f32x4 e2 = *(const f32x4*)(Et + (size_t)(d4 * 4 + 2) * NUM_CODES + c0);
        f32x4 e3 = *(const f32x4*)(Et + (size_t)(d4 * 4 + 3) * NUM_CODES + c0);
        #pragma unroll
        for (int t = 0; t < RT; ++t) {
            f32x4 z4 = *(const f32x4*)&zs[t][d4 * 4];
            acc[t] += z4.x * e0;
            acc[t] += z4.y * e1;
            acc[t] += z4.z * e2;
            acc[t] += z4.w * e3;
        }
    }

    f32x4 eq = *(const f32x4*)(esq + c0);
    #pragma unroll
    for (int t = 0; t < RT; ++t) {
        u64 p = ~0ull;
        #pragma unroll
        for (int r = 0; r < 4; ++r) {
            float v = fmaf(-2.0f, acc[t][r], eq[r]) + 4096.0f;
            u64 cand = ((u64)__float_as_uint(v) << 32) | (unsigned)(c0 + r);
            p = cand < p ? cand : p;
        }
        #pragma unroll
        for (int m = 1; m <= 32; m <<= 1) {
            u64 o = __shfl_xor(p, m, 64);
            p = o < p ? o : p;
        }
        int u = g * RT + t;
        if (lane == 0 && u < cnt) atomicMin(umin + u, p);
    }
}

__global__ void k_rwrite(const int* __restrict__ ulist, const int* __restrict__ ucount,
                         const u64* __restrict__ umin, int* __restrict__ out_idx) {
    int cnt = *ucount; if (cnt > UCAP) cnt = UCAP;
    int u = blockIdx.x * 256 + threadIdx.x;
    if (u < cnt) out_idx[ulist[u]] = (int)(umin[u] & 0xFFFFFFFFu);
}

// ---------------- gather z_q, loss partials, histogram ----------------
__global__ void k_gather(const float* __restrict__ Z, const float* __restrict__ E,
                         float* __restrict__ out,
                         float* __restrict__ loss_parts, unsigned* __restrict__ hist) {
    int wave = threadIdx.x >> 6, lane = threadIdx.x & 63;
    int token = blockIdx.x * 4 + wave;
    int* idxi = (int*)(out + IDX_OFF);
    int k = idxi[token];
    float4 z = *(const float4*)(Z + (size_t)token * EMBED_DIM + lane * 4);
    float4 qv = *(const float4*)(E + (size_t)k * EMBED_DIM + lane * 4);
    *(float4*)(out + (size_t)token * EMBED_DIM + lane * 4) = qv;
    float dx = qv.x - z.x, dy = qv.y - z.y, dz = qv.z - z.z, dw = qv.w - z.w;
    float s = dx * dx + dy * dy + dz * dz + dw * dw;
    #pragma unroll
    for (int off = 32; off; off >>= 1) s += __shfl_down(s, off, 64);
    if (lane == 0) {
        atomicAdd(loss_parts + (blockIdx.x & 1023), s);
        atomicAdd(hist + k, 1u);
        out[IDX_OFF + token] = (float)k;
    }
}

// ---------------- finalize loss + perplexity ----------------
__global__ void k_final(const float* __restrict__ loss_parts,
                        const unsigned* __restrict__ hist, float* __restrict__ out) {
    __shared__ float red[256];
    int t = threadIdx.x;
    float s = 0.0f;
    for (int i = t; i < 1024; i += 256) s += loss_parts[i];
    red[t] = s;
    __syncthreads();
    #pragma unroll
    for (int off = 128; off; off >>= 1) {
        if (t < off) red[t] += red[t + off];
        __syncthreads();
    }
    float loss = 0.1f * red[0] / (float)(N_TOKENS * EMBED_DIM);

    float h = 0.0f;
    for (int i = t; i < NUM_CODES; i += 256) {
        float p = (float)hist[i] / (float)N_TOKENS;
        h += p * logf(p + 1e-10f);
    }
    __syncthreads();
    red[t] = h;
    __syncthreads();
    #pragma unroll
    for (int off = 128; off; off >>= 1) {
        if (t < off) red[t] += red[t + off];
        __syncthreads();
    }
    if (t == 0) {
        out[LOSS_OFF]     = loss;
        out[LOSS_OFF + 1] = expf(-red[0]);
    }
}

extern "C" void kernel_launch(void* const* d_in, const int* in_sizes, int n_in,
                              void* d_out, int out_size, void* d_ws, size_t ws_size,
                              hipStream_t stream) {
    const float* Z = (const float*)d_in[0];
    const float* E = (const float*)d_in[1];
    float* out = (float*)d_out;
    char*  ob  = (char*)d_out;
    char*  ws  = (char*)d_ws;

    // scratch in d_out's upper z_q region (overwritten by gather afterwards):
    _Float16* Eh   = (_Float16*)(ob + 50331648);          // 48 MB: 2 MB packed
    float*    Et   = (float*)(ob + 54525952);             // 52 MB: 4 MB
    u64*      umin = (u64*)(ob + 58720256);               // 56 MB: 128 KB
    int*      idx  = (int*)(out + IDX_OFF);

    // small ws scratch (~100 KB)
    float*    esq        = (float*)ws;                    // 16 KB
    int*      ulist      = (int*)(ws + 16384);            // 64 KB
    int*      ucount     = (int*)(ws + 81920);            // 64 B
    float*    loss_parts = (float*)(ws + 81984);          // 4 KB
    unsigned* hist       = (unsigned*)(ws + 86080);       // 16 KB

    hipMemsetAsync(ws + 81920, 0, 64 + 4096 + 16384, stream);
    hipMemsetAsync(umin, 0xFF, (size_t)UCAP * 8, stream);

    k_convE      <<<(NUM_CODES * 32) / 256, 256, 0, stream>>>(E, Eh);
    k_esq        <<<NUM_CODES, 64, 0, stream>>>(E, esq);
    k_transpose  <<<dim3(NUM_CODES / 32, EMBED_DIM / 32), 256, 0, stream>>>(E, Et);
    k_argmin_mfma<<<N_TOKENS / 128, 512, 0, stream>>>(Z, Eh, esq, idx, ulist, ucount);
    k_refine     <<<4 * (UCAP / RT), 256, 0, stream>>>(Z, Et, esq, ulist, ucount, umin);
    k_rwrite     <<<UCAP / 256, 256, 0, stream>>>(ulist, ucount, umin, idx);
    k_gather     <<<N_TOKENS / 4, 256, 0, stream>>>(Z, E, out, loss_parts, hist);
    k_final      <<<1, 256, 0, stream>>>(loss_parts, hist, out);
}

// Round 9
// 339.027 us; speedup vs baseline: 1.1929x; 1.1068x over previous
//
#include <hip/hip_runtime.h>

#define N_TOKENS   65536
#define NUM_CODES  4096
#define EMBED_DIM  256

#define IDX_OFF  ((size_t)N_TOKENS * EMBED_DIM)
#define LOSS_OFF (IDX_OFF + N_TOKENS)

#define DELTA 0.2f
#define UCAP  16384
#define RT    8        // tokens per refine block

typedef _Float16 half8 __attribute__((ext_vector_type(8)));
typedef _Float16 half4 __attribute__((ext_vector_type(4)));
typedef float    f32x4 __attribute__((ext_vector_type(4)));
typedef unsigned long long u64;

__device__ __forceinline__ void gl_lds16(const void* g, void* l) {
    __builtin_amdgcn_global_load_lds(
        (const __attribute__((address_space(1))) unsigned int*)g,
        (__attribute__((address_space(3))) unsigned int*)l, 16, 0, 0);
}

// ---------------- fused prep: E -> esq (exact fp32) + Eh (B-fragment fp16) ----
// One block per code (4096 x 64 thr). Same loads feed both outputs.
// esq: identical shuffle reduction as the old k_esq (bit-identical result).
// Eh layout (unchanged): [ct=code>>4][kc=0..7][lane=q*16+(code&15)] x 16B;
// thread t covers kg=t>>1, 4-half slice (t&1) of the 8-half fragment slot.
__global__ void k_prep(const float* __restrict__ E, _Float16* __restrict__ Eh,
                       float* __restrict__ esq) {
    int n = blockIdx.x;
    int t = threadIdx.x;
    float4 v = *(const float4*)(E + (size_t)n * EMBED_DIM + t * 4);

    // esq reduction (identical to old k_esq)
    float s = v.x * v.x + v.y * v.y + v.z * v.z + v.w * v.w;
    #pragma unroll
    for (int off = 32; off; off >>= 1) s += __shfl_down(s, off, 64);
    if (t == 0) esq[n] = s;

    // convE: same conversions, same destination bytes as old k_convE
    int ct = n >> 4, l15 = n & 15;
    int kg = t >> 1, h2 = t & 1;
    int kc = kg >> 2, q = kg & 3;
    int lane = q * 16 + l15;
    half4 hv;
    hv[0] = (_Float16)v.x; hv[1] = (_Float16)v.y;
    hv[2] = (_Float16)v.z; hv[3] = (_Float16)v.w;
    *(half4*)(Eh + ((size_t)(ct * 8 + kc) * 64 + lane) * 8 + h2 * 4) = hv;
}

// ---------------- transpose E -> Et[256][4096] (for refine) ----------------
__global__ void k_transpose(const float* __restrict__ E, float* __restrict__ Et) {
    __shared__ float t[32][33];
    int tx = threadIdx.x & 31, ty = threadIdx.x >> 5;
    int c0 = blockIdx.x * 32, d0 = blockIdx.y * 32;
    #pragma unroll
    for (int i = 0; i < 4; ++i)
        t[ty + 8 * i][tx] = E[(size_t)(c0 + ty + 8 * i) * EMBED_DIM + d0 + tx];
    __syncthreads();
    #pragma unroll
    for (int i = 0; i < 4; ++i)
        Et[(size_t)(d0 + ty + 8 * i) * NUM_CODES + c0 + tx] = t[tx][ty + 8 * i];
}

// ---------------- fused fp16-MFMA distance + argmin/second (v3, restored) ----
// block: 256 thr = 4 waves, 128 tokens. wave = 64 tokens (w0 half) x 32 codes (w1 half).
// This is the byte-exact round-0 kernel (best measured: 160 us, MfmaUtil 37%).
// Eight structural rewrites (dbuf, counted-vmcnt, occupancy, tile-doubling) all
// regressed: v3 jointly minimizes per-wave LDS-read traffic (Tt=64 -> 2.1 GB)
// and iteration count among spill-free register configurations.
__launch_bounds__(256, 2)
__global__ void k_argmin_mfma(const float* __restrict__ Z, const _Float16* __restrict__ Eh,
                              const float* __restrict__ esq, int* __restrict__ out_idx,
                              int* __restrict__ ulist, int* __restrict__ ucount) {
    __shared__ __align__(16) _Float16 Bs[16384];   // 32 KB: 64 codes x 256 K
    __shared__ float esq_s[NUM_CODES];             // 16 KB

    const int tid  = threadIdx.x;
    const int lane = tid & 63;
    const int w    = tid >> 6;
    const int w0   = w >> 1;     // token half
    const int w1   = w & 1;      // code half
    const int l15  = lane & 15;
    const int q    = lane >> 4;
    const int tb   = blockIdx.x;

    for (int i = tid; i < NUM_CODES; i += 256) esq_s[i] = esq[i];

    // A-fragments: frag(rt,kc): lane holds Z[tb*128 + w0*64 + rt*16 + l15][kc*32 + q*8 + j]
    half8 A[4][8];
    const float* Zb = Z + ((size_t)tb * 128 + w0 * 64) * EMBED_DIM;
    #pragma unroll
    for (int rt = 0; rt < 4; ++rt) {
        const float* Zr = Zb + (rt * 16 + l15) * EMBED_DIM + q * 8;
        #pragma unroll
        for (int kc = 0; kc < 8; ++kc) {
            float4 a = *(const float4*)(Zr + kc * 32);
            float4 b = *(const float4*)(Zr + kc * 32 + 4);
            half8 hv;
            hv[0]=(_Float16)a.x; hv[1]=(_Float16)a.y; hv[2]=(_Float16)a.z; hv[3]=(_Float16)a.w;
            hv[4]=(_Float16)b.x; hv[5]=(_Float16)b.y; hv[6]=(_Float16)b.z; hv[7]=(_Float16)b.w;
            A[rt][kc] = hv;
        }
    }

    float best[16], sec[16];
    int   bidx[16];
    #pragma unroll
    for (int k = 0; k < 16; ++k) { best[k] = 1e30f; sec[k] = 1e30f; bidx[k] = 0; }

    const int cb = w1 * 2;   // this wave's 2 ct of the it-tile's 4

    for (int it = 0; it < NUM_CODES / 64; ++it) {
        __syncthreads();
        // stage 32 KB: 8 x 1KB per wave, layout identical to Eh (fragment-linear)
        const _Float16* src = Eh + (size_t)it * 16384 + (w * 8) * 512 + lane * 8;
        #pragma unroll
        for (int s = 0; s < 8; ++s)
            gl_lds16(src + s * 512, Bs + (w * 8 + s) * 512);
        __syncthreads();

        f32x4 acc[4][2];
        #pragma unroll
        for (int rt = 0; rt < 4; ++rt) { acc[rt][0] = (f32x4)0.0f; acc[rt][1] = (f32x4)0.0f; }

        #pragma unroll
        for (int kc = 0; kc < 8; ++kc) {
            half8 bf0 = *(const half8*)(Bs + ((cb + 0) * 8 + kc) * 512 + lane * 8);
            half8 bf1 = *(const half8*)(Bs + ((cb + 1) * 8 + kc) * 512 + lane * 8);
            #pragma unroll
            for (int rt = 0; rt < 4; ++rt) {
                acc[rt][0] = __builtin_amdgcn_mfma_f32_16x16x32_f16(A[rt][kc], bf0, acc[rt][0], 0, 0, 0);
                acc[rt][1] = __builtin_amdgcn_mfma_f32_16x16x32_f16(A[rt][kc], bf1, acc[rt][1], 0, 0, 0);
            }
        }

        // epilogue: d2 = esq - 2*dot; codes ascending (c=0 then c=1)
        int code0 = it * 64 + cb * 16 + l15;
        #pragma unroll
        for (int c = 0; c < 2; ++c) {
            float e  = esq_s[code0 + c * 16];
            int code = code0 + c * 16;
            #pragma unroll
            for (int rt = 0; rt < 4; ++rt)
                #pragma unroll
                for (int r = 0; r < 4; ++r) {
                    float v = fmaf(-2.0f, acc[rt][c][r], e);
                    int k = rt * 4 + r;
                    float ob = best[k];
                    bool t = v < ob;
                    best[k] = t ? v : ob;
                    sec[k]  = fminf(sec[k], t ? ob : v);
                    bidx[k] = t ? code : bidx[k];
                }
        }
    }

    // in-wave reduce over the 16 col-lanes (l15) of each quad group
    #pragma unroll
    for (int m = 1; m <= 8; m <<= 1) {
        #pragma unroll
        for (int k = 0; k < 16; ++k) {
            float ob = __shfl_xor(best[k], m, 64);
            float os = __shfl_xor(sec[k],  m, 64);
            int   oi = __shfl_xor(bidx[k], m, 64);
            float ns = fminf(fminf(sec[k], os), fmaxf(best[k], ob));
            bool t = (ob < best[k]) || (ob == best[k] && oi < bidx[k]);
            best[k] = t ? ob : best[k];
            bidx[k] = t ? oi : bidx[k];
            sec[k]  = ns;
        }
    }

    // cross-code-half merge via LDS (reuse Bs)
    __syncthreads();
    float* mb = (float*)Bs;          // [128][2]
    float* ms = mb + 256;
    int*   mi = (int*)(mb + 512);
    if (l15 == 0) {
        #pragma unroll
        for (int k = 0; k < 16; ++k) {
            int row = w0 * 64 + (k >> 2) * 16 + q * 4 + (k & 3);
            mb[row * 2 + w1] = best[k];
            ms[row * 2 + w1] = sec[k];
            mi[row * 2 + w1] = bidx[k];
        }
    }
    __syncthreads();
    if (tid < 128) {
        float b0 = mb[tid * 2], b1 = mb[tid * 2 + 1];
        float s0 = ms[tid * 2], s1 = ms[tid * 2 + 1];
        int   i0 = mi[tid * 2], i1 = mi[tid * 2 + 1];
        bool t = (b1 < b0) || (b1 == b0 && i1 < i0);
        float bb = t ? b1 : b0;
        int   ii = t ? i1 : i0;
        float ss = fminf(fminf(s0, s1), fmaxf(b0, b1));
        int token = tb * 128 + tid;
        out_idx[token] = ii;
        if (ss - bb < DELTA) {
            int p = atomicAdd(ucount, 1);
            if (p < UCAP) ulist[p] = token;
        }
    }
}

// ---------------- exact fp32 re-scan of uncertain tokens ----------------
__launch_bounds__(256)
__global__ void k_refine(const float* __restrict__ Z, const float* __restrict__ Et,
                         const float* __restrict__ esq, const int* __restrict__ ulist,
                         const int* __restrict__ ucount, u64* __restrict__ umin) {
    int cnt = *ucount; if (cnt > UCAP) cnt = UCAP;
    const int g   = blockIdx.x >> 2;
    const int qtr = blockIdx.x & 3;
    if (g * RT >= cnt) return;

    __shared__ float zs[RT][256];
    const int tid  = threadIdx.x;
    const int lane = tid & 63;

    #pragma unroll
    for (int t = 0; t < RT; ++t) {
        int u = g * RT + t;
        int tok = ulist[(u < cnt) ? u : g * RT];
        zs[t][tid] = Z[(size_t)tok * EMBED_DIM + tid];
    }
    __syncthreads();

    const int c0 = qtr * 1024 + tid * 4;
    f32x4 acc[RT];
    #pragma unroll
    for (int t = 0; t < RT; ++t) acc[t] = (f32x4)0.0f;

    for (int d4 = 0; d4 < 64; ++d4) {
        f32x4 e0 = *(const f32x4*)(Et + (size_t)(d4 * 4 + 0) * NUM_CODES + c0);
        f32x4 e1 = *(const f32x4*)(Et + (size_t)(d4 * 4 + 1) * NUM_CODES + c0);
        f32x4 e2 = *(const f32x4*)(Et + (size_t)(d4 * 4 + 2) * NUM_CODES + c0);
        f32x4 e3 = *(const f32x4*)(Et + (size_t)(d4 * 4 + 3) * NUM_CODES + c0);
        #pragma unroll
        for (int t = 0; t < RT; ++t) {
            f32x4 z4 = *(const f32x4*)&zs[t][d4 * 4];
            acc[t] += z4.x * e0;
            acc[t] += z4.y * e1;
            acc[t] += z4.z * e2;
            acc[t] += z4.w * e3;
        }
    }

    f32x4 eq = *(const f32x4*)(esq + c0);
    #pragma unroll
    for (int t = 0; t < RT; ++t) {
        u64 p = ~0ull;
        #pragma unroll
        for (int r = 0; r < 4; ++r) {
            float v = fmaf(-2.0f, acc[t][r], eq[r]) + 4096.0f;
            u64 cand = ((u64)__float_as_uint(v) << 32) | (unsigned)(c0 + r);
            p = cand < p ? cand : p;
        }
        #pragma unroll
        for (int m = 1; m <= 32; m <<= 1) {
            u64 o = __shfl_xor(p, m, 64);
            p = o < p ? o : p;
        }
        int u = g * RT + t;
        if (lane == 0 && u < cnt) atomicMin(umin + u, p);
    }
}

__global__ void k_rwrite(const int* __restrict__ ulist, const int* __restrict__ ucount,
                         const u64* __restrict__ umin, int* __restrict__ out_idx) {
    int cnt = *ucount; if (cnt > UCAP) cnt = UCAP;
    int u = blockIdx.x * 256 + threadIdx.x;
    if (u < cnt) out_idx[ulist[u]] = (int)(umin[u] & 0xFFFFFFFFu);
}

// ---------------- gather z_q, loss partials, histogram ----------------
__global__ void k_gather(const float* __restrict__ Z, const float* __restrict__ E,
                         float* __restrict__ out,
                         float* __restrict__ loss_parts, unsigned* __restrict__ hist) {
    int wave = threadIdx.x >> 6, lane = threadIdx.x & 63;
    int token = blockIdx.x * 4 + wave;
    int* idxi = (int*)(out + IDX_OFF);
    int k = idxi[token];
    float4 z = *(const float4*)(Z + (size_t)token * EMBED_DIM + lane * 4);
    float4 qv = *(const float4*)(E + (size_t)k * EMBED_DIM + lane * 4);
    *(float4*)(out + (size_t)token * EMBED_DIM + lane * 4) = qv;
    float dx = qv.x - z.x, dy = qv.y - z.y, dz = qv.z - z.z, dw = qv.w - z.w;
    float s = dx * dx + dy * dy + dz * dz + dw * dw;
    #pragma unroll
    for (int off = 32; off; off >>= 1) s += __shfl_down(s, off, 64);
    if (lane == 0) {
        atomicAdd(loss_parts + (blockIdx.x & 1023), s);
        atomicAdd(hist + k, 1u);
        out[IDX_OFF + token] = (float)k;
    }
}

// ---------------- finalize loss + perplexity ----------------
__global__ void k_final(const float* __restrict__ loss_parts,
                        const unsigned* __restrict__ hist, float* __restrict__ out) {
    __shared__ float red[256];
    int t = threadIdx.x;
    float s = 0.0f;
    for (int i = t; i < 1024; i += 256) s += loss_parts[i];
    red[t] = s;
    __syncthreads();
    #pragma unroll
    for (int off = 128; off; off >>= 1) {
        if (t < off) red[t] += red[t + off];
        __syncthreads();
    }
    float loss = 0.1f * red[0] / (float)(N_TOKENS * EMBED_DIM);

    float h = 0.0f;
    for (int i = t; i < NUM_CODES; i += 256) {
        float p = (float)hist[i] / (float)N_TOKENS;
        h += p * logf(p + 1e-10f);
    }
    __syncthreads();
    red[t] = h;
    __syncthreads();
    #pragma unroll
    for (int off = 128; off; off >>= 1) {
        if (t < off) red[t] += red[t + off];
        __syncthreads();
    }
    if (t == 0) {
        out[LOSS_OFF]     = loss;
        out[LOSS_OFF + 1] = expf(-red[0]);
    }
}

extern "C" void kernel_launch(void* const* d_in, const int* in_sizes, int n_in,
                              void* d_out, int out_size, void* d_ws, size_t ws_size,
                              hipStream_t stream) {
    const float* Z = (const float*)d_in[0];
    const float* E = (const float*)d_in[1];
    float* out = (float*)d_out;
    char*  ob  = (char*)d_out;
    char*  ws  = (char*)d_ws;

    // scratch in d_out's upper z_q region (overwritten by gather afterwards):
    _Float16* Eh   = (_Float16*)(ob + 50331648);          // 48 MB: 2 MB packed
    float*    Et   = (float*)(ob + 54525952);             // 52 MB: 4 MB
    u64*      umin = (u64*)(ob + 58720256);               // 56 MB: 128 KB
    int*      idx  = (int*)(out + IDX_OFF);

    // small ws scratch (~100 KB)
    float*    esq        = (float*)ws;                    // 16 KB
    int*      ulist      = (int*)(ws + 16384);            // 64 KB
    int*      ucount     = (int*)(ws + 81920);            // 64 B
    float*    loss_parts = (float*)(ws + 81984);          // 4 KB
    unsigned* hist       = (unsigned*)(ws + 86080);       // 16 KB

    hipMemsetAsync(ws + 81920, 0, 64 + 4096 + 16384, stream);
    hipMemsetAsync(umin, 0xFF, (size_t)UCAP * 8, stream);

    k_prep       <<<NUM_CODES, 64, 0, stream>>>(E, Eh, esq);
    k_transpose  <<<dim3(NUM_CODES / 32, EMBED_DIM / 32), 256, 0, stream>>>(E, Et);
    k_argmin_mfma<<<N_TOKENS / 128, 256, 0, stream>>>(Z, Eh, esq, idx, ulist, ucount);
    k_refine     <<<4 * (UCAP / RT), 256, 0, stream>>>(Z, Et, esq, ulist, ucount, umin);
    k_rwrite     <<<UCAP / 256, 256, 0, stream>>>(ulist, ucount, umin, idx);
    k_gather     <<<N_TOKENS / 4, 256, 0, stream>>>(Z, E, out, loss_parts, hist);
    k_final      <<<1, 256, 0, stream>>>(loss_parts, hist, out);
}